// Round 3
// baseline (430.928 us; speedup 1.0000x reference)
//
#include <hip/hip_runtime.h>

// Problem constants (match reference file)
#define T_TOK 10
#define NN    4096
#define NE    65536
#define DF    128
#define DPE   32
#define LSPD  4
#define BB    64

#define TN    (T_TOK + NN)            // 4106 nodes per graph after token prepend
#define EI    (T_TOK * (T_TOK - 1))   // 90 inner prompt edges
#define EC    (2 * T_TOK * NN)        // 81920 undirected cross edges
#define ETOT  (EI + NE + EC)          // 147546 edges per graph (even)
#define BE    (BB * ETOT)             // 9,442,944 total edges

// Output region sizes (flat f32 elements, concatenated in return order)
#define SX (BB * TN * DF)             // 33,636,352  x
#define SP (BB * TN * DPE)            //  8,409,088  pe
#define SE (2 * BE)                   // 18,885,888  edge_index
#define SW (BE)                       //  9,442,944  edge_weight

// Unified work-unit space:
//   [0, UX)            : one float4 of x
//   [UX, UX+UP)        : one float4 of pe
//   [.., .. + UE)      : one PAIR of edges (float2 stores; all segment
//                        boundaries are even so a pair never straddles)
//   [.., .. + BB)      : one root element
#define UX (SX / 4)                   // 8,409,088
#define UP (SP / 4)                   // 2,102,272
#define UE (BE / 2)                   // 4,721,472
#define PEB (ETOT / 2)                // 73,773 edge-pairs per batch
#define UTOT (UX + UP + UE + BB)      // 15,232,896

typedef float f32x4 __attribute__((ext_vector_type(4)));
typedef float f32x2 __attribute__((ext_vector_type(2)));
typedef int   i32x2 __attribute__((ext_vector_type(2)));

__global__ __launch_bounds__(256) void k_all(
    const f32x4* __restrict__ gx, const f32x4* __restrict__ gpe,
    const int* __restrict__ gei, const int* __restrict__ spd,
    const int* __restrict__ groot,
    const f32x4* __restrict__ tok, const f32x4* __restrict__ tokpe,
    const float* __restrict__ swp, const float* __restrict__ ewp,
    float* __restrict__ out)
{
    const int stride = gridDim.x * blockDim.x;
    for (int u = blockIdx.x * blockDim.x + threadIdx.x; u < UTOT; u += stride) {
        if (u < UX) {
            // ---- x: [B*TN, 128] f32, 32 float4 per row
            int row = u >> 5, c = u & 31;
            int b = row / TN, lr = row - b * TN;
            f32x4 v;
            if (lr < T_TOK) v = tok[lr * 32 + c];
            else            v = __builtin_nontemporal_load(&gx[(b * NN + lr - T_TOK) * 32 + c]);
            __builtin_nontemporal_store(v, &((f32x4*)out)[u]);
        } else if (u < UX + UP) {
            // ---- pe: [B*TN, 32] f32, 8 float4 per row
            int q = u - UX;
            int row = q >> 3, c = q & 7;
            int b = row / TN, lr = row - b * TN;
            f32x4 v;
            if (lr < T_TOK) v = tokpe[lr * 8 + c];
            else            v = __builtin_nontemporal_load(&gpe[(b * NN + lr - T_TOK) * 8 + c]);
            __builtin_nontemporal_store(v, &((f32x4*)out)[u]);   // pe starts at float4 index UX
        } else if (u < UX + UP + UE) {
            // ---- edges: one pair (e0, e0+1) within one batch b
            int p  = u - (UX + UP);
            int b  = p / PEB;
            int e0 = 2 * (p - b * PEB);
            int base = b * TN;
            f32x2 s2, d2, w2;
            if (e0 < EI) {
                // complete token graph minus self loops, row-major
                int e1 = e0 + 1;
                int i0 = e0 / (T_TOK - 1), k0 = e0 - i0 * (T_TOK - 1);
                int i1 = e1 / (T_TOK - 1), k1 = e1 - i1 * (T_TOK - 1);
                int j0 = k0 + (k0 >= i0 ? 1 : 0);
                int j1 = k1 + (k1 >= i1 ? 1 : 0);
                float w = swp[0];
                s2 = (f32x2){(float)(i0 + base), (float)(i1 + base)};
                d2 = (f32x2){(float)(j0 + base), (float)(j1 + base)};
                w2 = (f32x2){w, w};
            } else if (e0 < EI + NE) {
                int ge = e0 - EI;   // even
                i32x2 sa = __builtin_nontemporal_load((const i32x2*)&gei[(2 * b + 0) * NE + ge]);
                i32x2 da = __builtin_nontemporal_load((const i32x2*)&gei[(2 * b + 1) * NE + ge]);
                s2 = (f32x2){(float)(sa.x + T_TOK + base), (float)(sa.y + T_TOK + base)};
                d2 = (f32x2){(float)(da.x + T_TOK + base), (float)(da.y + T_TOK + base)};
                w2 = (f32x2){1.0f, 1.0f};
            } else {
                int c = e0 - EI - NE;  // even, in [0, 81920)
                int n, s0, d0, s1, d1;
                if (c < T_TOK * NN) {              // forward: token -> node
                    int t = c >> 12; n = c & (NN - 1);
                    s0 = t;          d0 = n + T_TOK;
                    s1 = t;          d1 = n + 1 + T_TOK;
                } else {                           // reversed: node -> token
                    int c2 = c - T_TOK * NN;
                    int t = c2 >> 12; n = c2 & (NN - 1);
                    s0 = n + T_TOK;     d0 = t;
                    s1 = n + 1 + T_TOK; d1 = t;
                }
                i32x2 sv = *(const i32x2*)&spd[b * NN + n];   // n even -> aligned
                int v0 = min(max(sv.x, 0), LSPD);
                int v1 = min(max(sv.y, 0), LSPD);
                w2 = (f32x2){ewp[v0], ewp[v1]};
                s2 = (f32x2){(float)(s0 + base), (float)(s1 + base)};
                d2 = (f32x2){(float)(d0 + base), (float)(d1 + base)};
            }
            int i0 = b * ETOT + e0;                // flat edge index (even)
            float* oei = out + (SX + SP);
            float* oew = out + (SX + SP + SE);
            __builtin_nontemporal_store(s2, (f32x2*)&oei[i0]);
            __builtin_nontemporal_store(d2, (f32x2*)&oei[BE + i0]);
            __builtin_nontemporal_store(w2, (f32x2*)&oew[i0]);
        } else {
            // ---- root
            int b = u - (UX + UP + UE);
            out[SX + SP + SE + SW + b] = (float)(groot[b] + T_TOK + b * TN);
        }
    }
}

extern "C" void kernel_launch(void* const* d_in, const int* in_sizes, int n_in,
                              void* d_out, int out_size, void* d_ws, size_t ws_size,
                              hipStream_t stream) {
    const f32x4* g_x      = (const f32x4*)d_in[0];
    const f32x4* g_pe     = (const f32x4*)d_in[1];
    const int*   g_ei     = (const int*)d_in[2];
    const int*   g_spd    = (const int*)d_in[3];
    const int*   g_root   = (const int*)d_in[4];
    const f32x4* token    = (const f32x4*)d_in[5];
    const f32x4* token_pe = (const f32x4*)d_in[6];
    const float* shared_w = (const float*)d_in[7];
    const float* ew_param = (const float*)d_in[8];

    k_all<<<2048, 256, 0, stream>>>(g_x, g_pe, g_ei, g_spd, g_root,
                                    token, token_pe, shared_w, ew_param,
                                    (float*)d_out);
}